// Round 1
// baseline (1423.634 us; speedup 1.0000x reference)
//
#include <hip/hip_runtime.h>
#include <cstddef>

// Problem constants
constexpr int B_  = 2;
constexpr int S_  = 2048;
constexpr int H_  = 1024;
constexpr int NH_ = 16;
constexpr int DK_ = 64;
constexpr int M_  = B_ * S_;   // 4096 rows

// ---------------------------------------------------------------------------
// GEMM: C = A(MxK) * W(NxK)^T + bias, K = N = H_ = 1024.
// PERM=true  : write C in [B,NH,S,DK] layout (head-split + transposed)
// PERM=false : write C in plain [M,N] row-major
// Tiles: BM=BN=64, BK=16; 256 threads; 4x4 microtile per thread.
// ---------------------------------------------------------------------------
template <bool PERM>
__global__ __launch_bounds__(256) void gemm_xwt(
    const float* __restrict__ A,     // [M, K]
    const float* __restrict__ W,     // [N, K]
    const float* __restrict__ bias,  // [N]
    float* __restrict__ C)
{
    constexpr int K  = H_;
    constexpr int BM = 64, BN = 64, BK = 16;
    // +4 pad keeps float4 row reads 16B-aligned and spreads banks
    __shared__ float As[BK][BM + 4];
    __shared__ float Ws[BK][BN + 4];

    const int t  = threadIdx.x;
    const int m0 = blockIdx.y * BM;
    const int n0 = blockIdx.x * BN;

    // staging-load mapping: each thread loads one float4 of A and of W
    const int lrow = t >> 2;          // 0..63
    const int lkq  = (t & 3) * 4;     // 0,4,8,12

    // compute mapping: 16x16 thread grid, 4x4 microtile
    const int r0 = (t >> 4) * 4;      // row offset in tile
    const int c0 = (t & 15) * 4;      // col offset in tile

    float acc[4][4] = {};

    for (int k0 = 0; k0 < K; k0 += BK) {
        const float4 av = *reinterpret_cast<const float4*>(
            &A[(size_t)(m0 + lrow) * K + k0 + lkq]);
        const float4 wv = *reinterpret_cast<const float4*>(
            &W[(size_t)(n0 + lrow) * K + k0 + lkq]);
        As[lkq + 0][lrow] = av.x;
        As[lkq + 1][lrow] = av.y;
        As[lkq + 2][lrow] = av.z;
        As[lkq + 3][lrow] = av.w;
        Ws[lkq + 0][lrow] = wv.x;
        Ws[lkq + 1][lrow] = wv.y;
        Ws[lkq + 2][lrow] = wv.z;
        Ws[lkq + 3][lrow] = wv.w;
        __syncthreads();

#pragma unroll
        for (int kk = 0; kk < BK; ++kk) {
            const float4 a = *reinterpret_cast<const float4*>(&As[kk][r0]);
            const float4 w = *reinterpret_cast<const float4*>(&Ws[kk][c0]);
            acc[0][0] += a.x * w.x; acc[0][1] += a.x * w.y;
            acc[0][2] += a.x * w.z; acc[0][3] += a.x * w.w;
            acc[1][0] += a.y * w.x; acc[1][1] += a.y * w.y;
            acc[1][2] += a.y * w.z; acc[1][3] += a.y * w.w;
            acc[2][0] += a.z * w.x; acc[2][1] += a.z * w.y;
            acc[2][2] += a.z * w.z; acc[2][3] += a.z * w.w;
            acc[3][0] += a.w * w.x; acc[3][1] += a.w * w.y;
            acc[3][2] += a.w * w.z; acc[3][3] += a.w * w.w;
        }
        __syncthreads();
    }

    const float4 bv = *reinterpret_cast<const float4*>(&bias[n0 + c0]);
#pragma unroll
    for (int i = 0; i < 4; ++i) {
        const int m = m0 + r0 + i;
        float4 ov;
        ov.x = acc[i][0] + bv.x;
        ov.y = acc[i][1] + bv.y;
        ov.z = acc[i][2] + bv.z;
        ov.w = acc[i][3] + bv.w;
        if (PERM) {
            // n-tile (64-wide, 64-aligned) spans exactly one head: h=n>>6
            const int n = n0 + c0;
            const int b = m >> 11;            // m / S_
            const int s = m & (S_ - 1);
            const int h = n >> 6;
            const int d = n & 63;
            float* dst = &C[(((size_t)b * NH_ + h) * S_ + s) * DK_ + d];
            *reinterpret_cast<float4*>(dst) = ov;
        } else {
            *reinterpret_cast<float4*>(&C[(size_t)m * H_ + n0 + c0]) = ov;
        }
    }
}

// ---------------------------------------------------------------------------
// Flash attention, fp32. One block = one (b,h) x 32-query tile.
// Online softmax over key tiles of 32. DK=64.
// ctx written in concat layout [B,S,H].
// ---------------------------------------------------------------------------
__global__ __launch_bounds__(256) void attn_flash(
    const float* __restrict__ qh,   // [B,NH,S,DK]
    const float* __restrict__ kh,
    const float* __restrict__ vh,
    float* __restrict__ ctxc)       // [B,S,H]
{
    constexpr int BQ = 32, BK = 32;
    __shared__ float Qs[BQ][DK_ + 4];
    __shared__ float Ks[BK][DK_ + 4];
    __shared__ float Vs[BK][DK_ + 4];
    __shared__ float Ss[BQ][BK + 1];
    __shared__ float mrow[BQ], lrow[BQ], arow[BQ];

    const int t  = threadIdx.x;
    const int q0 = blockIdx.x * BQ;
    const int bh = blockIdx.y;          // b*NH + h
    const int b  = bh / NH_;
    const int h  = bh % NH_;

    const float* qb = qh + (size_t)bh * S_ * DK_;
    const float* kb = kh + (size_t)bh * S_ * DK_;
    const float* vb = vh + (size_t)bh * S_ * DK_;

    // load Q tile: 32x64 floats, 8 per thread
    {
        const int row = t >> 3;
        const int col = (t & 7) * 8;
        const float4* src =
            reinterpret_cast<const float4*>(&qb[(size_t)(q0 + row) * DK_ + col]);
        *reinterpret_cast<float4*>(&Qs[row][col])     = src[0];
        *reinterpret_cast<float4*>(&Qs[row][col + 4]) = src[1];
    }
    if (t < BQ) { mrow[t] = -1e30f; lrow[t] = 0.f; }

    const int r  = t >> 3;   // query row this thread owns (0..31)
    const int tc = t & 7;    // d-group (8 floats) / score col group
    float o[8] = {};

    __syncthreads();

    for (int j0 = 0; j0 < S_; j0 += BK) {
        // stage K,V tiles
        {
            const int row = t >> 3;
            const int col = (t & 7) * 8;
            const float4* ks = reinterpret_cast<const float4*>(
                &kb[(size_t)(j0 + row) * DK_ + col]);
            *reinterpret_cast<float4*>(&Ks[row][col])     = ks[0];
            *reinterpret_cast<float4*>(&Ks[row][col + 4]) = ks[1];
            const float4* vs = reinterpret_cast<const float4*>(
                &vb[(size_t)(j0 + row) * DK_ + col]);
            *reinterpret_cast<float4*>(&Vs[row][col])     = vs[0];
            *reinterpret_cast<float4*>(&Vs[row][col + 4]) = vs[1];
        }
        __syncthreads();

        // scores: row r, cols j = tc + 8u (u=0..3), conflict-free bank stride
        float sc[4] = {0.f, 0.f, 0.f, 0.f};
#pragma unroll
        for (int kk = 0; kk < DK_; kk += 4) {
            const float4 qv = *reinterpret_cast<const float4*>(&Qs[r][kk]);
#pragma unroll
            for (int u = 0; u < 4; ++u) {
                const float4 kv =
                    *reinterpret_cast<const float4*>(&Ks[tc + 8 * u][kk]);
                sc[u] += qv.x * kv.x + qv.y * kv.y + qv.z * kv.z + qv.w * kv.w;
            }
        }
#pragma unroll
        for (int u = 0; u < 4; ++u) Ss[r][tc + 8 * u] = sc[u] * 0.125f;
        __syncthreads();

        // online softmax, one thread per row
        if (t < BQ) {
            const float mo = mrow[t];
            float mx = mo;
#pragma unroll
            for (int j = 0; j < BK; ++j) mx = fmaxf(mx, Ss[t][j]);
            const float a = __expf(mo - mx);
            float sum = 0.f;
#pragma unroll
            for (int j = 0; j < BK; ++j) {
                const float p = __expf(Ss[t][j] - mx);
                Ss[t][j] = p;
                sum += p;
            }
            mrow[t] = mx;
            lrow[t] = lrow[t] * a + sum;
            arow[t] = a;
        }
        __syncthreads();

        // rescale + accumulate ctx
        const float a = arow[r];
#pragma unroll
        for (int dd = 0; dd < 8; ++dd) o[dd] *= a;
#pragma unroll
        for (int j = 0; j < BK; ++j) {
            const float p = Ss[r][j];
            const float4 v0 =
                *reinterpret_cast<const float4*>(&Vs[j][tc * 8]);
            const float4 v1 =
                *reinterpret_cast<const float4*>(&Vs[j][tc * 8 + 4]);
            o[0] += p * v0.x; o[1] += p * v0.y;
            o[2] += p * v0.z; o[3] += p * v0.w;
            o[4] += p * v1.x; o[5] += p * v1.y;
            o[6] += p * v1.z; o[7] += p * v1.w;
        }
        __syncthreads();
    }

    const float inv = 1.f / lrow[r];
    const int s = q0 + r;
    float* dst = &ctxc[((size_t)b * S_ + s) * H_ + h * DK_ + tc * 8];
    float4 o0, o1;
    o0.x = o[0] * inv; o0.y = o[1] * inv; o0.z = o[2] * inv; o0.w = o[3] * inv;
    o1.x = o[4] * inv; o1.y = o[5] * inv; o1.z = o[6] * inv; o1.w = o[7] * inv;
    *reinterpret_cast<float4*>(dst)      = o0;
    *reinterpret_cast<float4*>(&dst[4])  = o1;
}

// ---------------------------------------------------------------------------
extern "C" void kernel_launch(void* const* d_in, const int* in_sizes, int n_in,
                              void* d_out, int out_size, void* d_ws,
                              size_t ws_size, hipStream_t stream)
{
    (void)in_sizes; (void)n_in; (void)out_size; (void)ws_size;
    // setup_inputs order: q, v, k, Wq, bq, Wk, bk, Wv, bv, Wo, bo
    const float* q  = (const float*)d_in[0];
    const float* v  = (const float*)d_in[1];
    const float* k  = (const float*)d_in[2];
    const float* Wq = (const float*)d_in[3];
    const float* bq = (const float*)d_in[4];
    const float* Wk = (const float*)d_in[5];
    const float* bk = (const float*)d_in[6];
    const float* Wv = (const float*)d_in[7];
    const float* bv = (const float*)d_in[8];
    const float* Wo = (const float*)d_in[9];
    const float* bo = (const float*)d_in[10];
    float* out = (float*)d_out;

    // workspace: 4 x (B*NH*S*DK = 4,194,304 floats = 16 MB) = 64 MB
    constexpr size_t NELT = (size_t)B_ * NH_ * S_ * DK_;
    float* ws   = (float*)d_ws;
    float* qh   = ws;
    float* kh   = ws + NELT;
    float* vh   = ws + 2 * NELT;
    float* ctxc = ws + 3 * NELT;

    const dim3 gg(H_ / 64, M_ / 64);   // 16 x 64 tiles
    const dim3 bb(256);

    gemm_xwt<true><<<gg, bb, 0, stream>>>(q, Wq, bq, qh);
    gemm_xwt<true><<<gg, bb, 0, stream>>>(k, Wk, bk, kh);
    gemm_xwt<true><<<gg, bb, 0, stream>>>(v, Wv, bv, vh);

    attn_flash<<<dim3(S_ / 32, B_ * NH_), bb, 0, stream>>>(qh, kh, vh, ctxc);

    gemm_xwt<false><<<gg, bb, 0, stream>>>(ctxc, Wo, bo, out);
}

// Round 2
// 331.282 us; speedup vs baseline: 4.2973x; 4.2973x over previous
//
#include <hip/hip_runtime.h>
#include <cstddef>
#include <cstdint>

typedef _Float16 f16x8 __attribute__((ext_vector_type(8)));
typedef float    f32x4 __attribute__((ext_vector_type(4)));

constexpr int B_  = 2;
constexpr int S_  = 2048;
constexpr int H_  = 1024;
constexpr int NH_ = 16;
constexpr int DK_ = 64;
constexpr int M_  = B_ * S_;   // 4096
constexpr int K_  = H_;        // 1024

#define MFMA16(a, b, c) __builtin_amdgcn_mfma_f32_16x16x32_f16((a), (b), (c), 0, 0, 0)

// ---------------------------------------------------------------------------
// fp32 -> f16 conversion, 7 tensors in one launch (blockIdx.y = segment)
// ---------------------------------------------------------------------------
struct CvtArgs {
    const float* s[7];
    _Float16*    d[7];
    int          n[7];
};

__global__ __launch_bounds__(256) void cvt7(CvtArgs a)
{
    const int seg = blockIdx.y;
    const int i = (blockIdx.x * 256 + threadIdx.x) * 8;
    if (i + 8 <= a.n[seg]) {
        const float4 v0 = *reinterpret_cast<const float4*>(a.s[seg] + i);
        const float4 v1 = *reinterpret_cast<const float4*>(a.s[seg] + i + 4);
        f16x8 o;
        o[0] = (_Float16)v0.x; o[1] = (_Float16)v0.y;
        o[2] = (_Float16)v0.z; o[3] = (_Float16)v0.w;
        o[4] = (_Float16)v1.x; o[5] = (_Float16)v1.y;
        o[6] = (_Float16)v1.z; o[7] = (_Float16)v1.w;
        *reinterpret_cast<f16x8*>(a.d[seg] + i) = o;
    }
}

// ---------------------------------------------------------------------------
// MFMA GEMM: C = A(MxK) * W(NxK)^T + bias, f16 inputs, fp32 accumulate.
// BM=128, BN=64 (one head), BK=32. 256 threads = 4 waves; wave w owns rows
// [w*32, w*32+32) x all 64 cols = 2x4 tiles of 16x16 -> 8 MFMAs / K-iter.
// MODE 0: f16 out, [B,NH,S,DK] (head-permuted), epilogue scale (Q: 1/8)
// MODE 1: f16 out, [B,NH,DK,S] (transposed for PV B-operand)
// MODE 2: fp32 out, plain [M,N]
// LDS leading dim 40 f16 (80 B): 16B-aligned b128, 2-way banks only (free).
// ---------------------------------------------------------------------------
template <int MODE>
__global__ __launch_bounds__(256) void gemm16(
    const _Float16* __restrict__ A, const _Float16* __restrict__ W,
    const float* __restrict__ bias, void* __restrict__ Cout, float scale)
{
    constexpr int BM = 128, BN = 64, BK = 32, LD = 40;
    __shared__ _Float16 As[BM][LD];
    __shared__ _Float16 Ws[BN][LD];

    const int t = threadIdx.x;
    const int w = t >> 6, lane = t & 63, quad = lane >> 4, l16 = lane & 15;
    const int m0 = blockIdx.y * BM;
    const int n0 = blockIdx.x * BN;

    f32x4 acc[2][4];
#pragma unroll
    for (int i = 0; i < 2; ++i)
#pragma unroll
        for (int j = 0; j < 4; ++j) acc[i][j] = (f32x4){0.f, 0.f, 0.f, 0.f};

    for (int k0 = 0; k0 < K_; k0 += BK) {
        // stage A: 128 rows x 4 chunks(16B) = 512 chunks, 2 passes
#pragma unroll
        for (int p = 0; p < 2; ++p) {
            const int c = t + p * 256;
            const int row = c >> 2, c8 = (c & 3) * 8;
            *reinterpret_cast<f16x8*>(&As[row][c8]) =
                *reinterpret_cast<const f16x8*>(&A[(size_t)(m0 + row) * K_ + k0 + c8]);
        }
        // stage W: 64 rows x 4 chunks = 256 chunks, 1 pass
        {
            const int row = t >> 2, c8 = (t & 3) * 8;
            *reinterpret_cast<f16x8*>(&Ws[row][c8]) =
                *reinterpret_cast<const f16x8*>(&W[(size_t)(n0 + row) * K_ + k0 + c8]);
        }
        __syncthreads();

        f16x8 af[2], bf[4];
#pragma unroll
        for (int i = 0; i < 2; ++i)
            af[i] = *reinterpret_cast<const f16x8*>(&As[w * 32 + i * 16 + l16][quad * 8]);
#pragma unroll
        for (int j = 0; j < 4; ++j)
            bf[j] = *reinterpret_cast<const f16x8*>(&Ws[j * 16 + l16][quad * 8]);
#pragma unroll
        for (int i = 0; i < 2; ++i)
#pragma unroll
            for (int j = 0; j < 4; ++j)
                acc[i][j] = MFMA16(af[i], bf[j], acc[i][j]);
        __syncthreads();
    }

    // epilogue
    float bv[4];
#pragma unroll
    for (int j = 0; j < 4; ++j) bv[j] = bias[n0 + j * 16 + l16];

#pragma unroll
    for (int i = 0; i < 2; ++i) {
#pragma unroll
        for (int j = 0; j < 4; ++j) {
#pragma unroll
            for (int r = 0; r < 4; ++r) {
                const float val = (acc[i][j][r] + bv[j]) * scale;
                const int m = m0 + w * 32 + i * 16 + quad * 4 + r;
                const int d = j * 16 + l16;
                if (MODE == 0) {
                    const int b = m >> 11, s = m & (S_ - 1);
                    ((_Float16*)Cout)[(((size_t)b * NH_ + blockIdx.x) * S_ + s) * DK_ + d] =
                        (_Float16)val;
                } else if (MODE == 1) {
                    const int b = m >> 11, s = m & (S_ - 1);
                    ((_Float16*)Cout)[(((size_t)b * NH_ + blockIdx.x) * DK_ + d) * S_ + s] =
                        (_Float16)val;
                } else {
                    ((float*)Cout)[(size_t)m * H_ + n0 + d] = val;
                }
            }
        }
    }
}

// ---------------------------------------------------------------------------
// MFMA flash attention. Block = (b,h) x 64-query tile, 256 thr = 4 waves.
// Wave w owns the 16-row strip [w*16, w*16+16). Key tiles of 64.
// qh pre-scaled by 1/sqrt(DK). vt is [B,NH,DK,S] so PV B-frags are contiguous.
// Layouts (16x16x32 f16, guide-verified): A[m=lane&15][k=quad*8+j],
// B[k=quad*8+j][n=lane&15], C/D: col=lane&15, row=quad*4+reg.
// ---------------------------------------------------------------------------
__global__ __launch_bounds__(256) void attn_mfma(
    const _Float16* __restrict__ qh, const _Float16* __restrict__ kh,
    const _Float16* __restrict__ vt, _Float16* __restrict__ ctx)
{
    constexpr int LDT = 72;   // 144 B rows: b128 reads are 2-way (free)
    __shared__ _Float16 Qs[64][LDT];
    __shared__ _Float16 Ks[64][LDT];
    __shared__ _Float16 Vs[64][LDT];   // V^T tile: [d][key]
    __shared__ _Float16 Ps[64][LDT];

    const int t = threadIdx.x;
    const int w = t >> 6, lane = t & 63, quad = lane >> 4, l16 = lane & 15;
    const int q0 = blockIdx.x * 64;
    const int bh = blockIdx.y;

    const _Float16* qb = qh + (size_t)bh * S_ * DK_;
    const _Float16* kb = kh + (size_t)bh * S_ * DK_;
    const _Float16* vb = vt + (size_t)bh * DK_ * S_;

    // stage Q tile (64 x 64)
#pragma unroll
    for (int p = 0; p < 2; ++p) {
        const int c = t + p * 256;
        const int row = c >> 3, c8 = (c & 7) * 8;
        *reinterpret_cast<f16x8*>(&Qs[row][c8]) =
            *reinterpret_cast<const f16x8*>(&qb[(size_t)(q0 + row) * DK_ + c8]);
    }

    f32x4 o[4];
#pragma unroll
    for (int dt = 0; dt < 4; ++dt) o[dt] = (f32x4){0.f, 0.f, 0.f, 0.f};
    float m_[4], l_[4];
#pragma unroll
    for (int r = 0; r < 4; ++r) { m_[r] = -1e30f; l_[r] = 0.f; }

    for (int j0 = 0; j0 < S_; j0 += 64) {
#pragma unroll
        for (int p = 0; p < 2; ++p) {
            const int c = t + p * 256;
            const int row = c >> 3, c8 = (c & 7) * 8;
            *reinterpret_cast<f16x8*>(&Ks[row][c8]) =
                *reinterpret_cast<const f16x8*>(&kb[(size_t)(j0 + row) * DK_ + c8]);
            *reinterpret_cast<f16x8*>(&Vs[row][c8]) =
                *reinterpret_cast<const f16x8*>(&vb[(size_t)row * S_ + j0 + c8]);
        }
        __syncthreads();

        // S = Q K^T for this wave's 16-row strip (4 col tiles x k={0,32})
        const f16x8 aq0 = *reinterpret_cast<const f16x8*>(&Qs[w * 16 + l16][quad * 8]);
        const f16x8 aq1 = *reinterpret_cast<const f16x8*>(&Qs[w * 16 + l16][32 + quad * 8]);
        f32x4 sc[4];
#pragma unroll
        for (int ct = 0; ct < 4; ++ct) {
            sc[ct] = (f32x4){0.f, 0.f, 0.f, 0.f};
            const f16x8 b0 = *reinterpret_cast<const f16x8*>(&Ks[ct * 16 + l16][quad * 8]);
            const f16x8 b1 = *reinterpret_cast<const f16x8*>(&Ks[ct * 16 + l16][32 + quad * 8]);
            sc[ct] = MFMA16(aq0, b0, sc[ct]);
            sc[ct] = MFMA16(aq1, b1, sc[ct]);
        }

        // online softmax per row (rows quad*4+r; 16 lanes/quad redundant)
#pragma unroll
        for (int r = 0; r < 4; ++r) {
            float mx = fmaxf(fmaxf(sc[0][r], sc[1][r]), fmaxf(sc[2][r], sc[3][r]));
            mx = fmaxf(mx, __shfl_xor(mx, 1));
            mx = fmaxf(mx, __shfl_xor(mx, 2));
            mx = fmaxf(mx, __shfl_xor(mx, 4));
            mx = fmaxf(mx, __shfl_xor(mx, 8));
            const float mn = fmaxf(m_[r], mx);
            const float al = __expf(m_[r] - mn);
            float rs = 0.f;
#pragma unroll
            for (int ct = 0; ct < 4; ++ct) {
                const float p = __expf(sc[ct][r] - mn);
                sc[ct][r] = p;
                rs += p;
            }
            rs += __shfl_xor(rs, 1);
            rs += __shfl_xor(rs, 2);
            rs += __shfl_xor(rs, 4);
            rs += __shfl_xor(rs, 8);
            l_[r] = l_[r] * al + rs;
            m_[r] = mn;
#pragma unroll
            for (int dt = 0; dt < 4; ++dt) o[dt][r] *= al;
#pragma unroll
            for (int ct = 0; ct < 4; ++ct)
                Ps[w * 16 + quad * 4 + r][ct * 16 + l16] = (_Float16)sc[ct][r];
        }

        // O += P V  (Ps rows are wave-private: same-wave DS order suffices)
        const f16x8 pa0 = *reinterpret_cast<const f16x8*>(&Ps[w * 16 + l16][quad * 8]);
        const f16x8 pa1 = *reinterpret_cast<const f16x8*>(&Ps[w * 16 + l16][32 + quad * 8]);
#pragma unroll
        for (int dt = 0; dt < 4; ++dt) {
            const f16x8 vb0 = *reinterpret_cast<const f16x8*>(&Vs[dt * 16 + l16][quad * 8]);
            const f16x8 vb1 = *reinterpret_cast<const f16x8*>(&Vs[dt * 16 + l16][32 + quad * 8]);
            o[dt] = MFMA16(pa0, vb0, o[dt]);
            o[dt] = MFMA16(pa1, vb1, o[dt]);
        }
        __syncthreads();
    }

    // normalize, round-trip through LDS for coalesced f16 stores
    float inv[4];
#pragma unroll
    for (int r = 0; r < 4; ++r) inv[r] = 1.f / l_[r];
#pragma unroll
    for (int dt = 0; dt < 4; ++dt)
#pragma unroll
        for (int r = 0; r < 4; ++r)
            Ps[w * 16 + quad * 4 + r][dt * 16 + l16] = (_Float16)(o[dt][r] * inv[r]);
    __syncthreads();

    const int b = bh >> 4, h = bh & 15;
#pragma unroll
    for (int p = 0; p < 2; ++p) {
        const int c = t + p * 256;
        const int row = c >> 3, c8 = (c & 7) * 8;
        *reinterpret_cast<f16x8*>(&ctx[((size_t)b * S_ + q0 + row) * H_ + h * 64 + c8]) =
            *reinterpret_cast<const f16x8*>(&Ps[row][c8]);
    }
}

// ---------------------------------------------------------------------------
extern "C" void kernel_launch(void* const* d_in, const int* in_sizes, int n_in,
                              void* d_out, int out_size, void* d_ws,
                              size_t ws_size, hipStream_t stream)
{
    (void)in_sizes; (void)n_in; (void)out_size; (void)ws_size;
    // setup_inputs order: q, v, k, Wq, bq, Wk, bk, Wv, bv, Wo, bo
    const float* q  = (const float*)d_in[0];
    const float* v  = (const float*)d_in[1];
    const float* k  = (const float*)d_in[2];
    const float* Wq = (const float*)d_in[3];
    const float* bq = (const float*)d_in[4];
    const float* Wk = (const float*)d_in[5];
    const float* bk = (const float*)d_in[6];
    const float* Wv = (const float*)d_in[7];
    const float* bv = (const float*)d_in[8];
    const float* Wo = (const float*)d_in[9];
    const float* bo = (const float*)d_in[10];
    float* out = (float*)d_out;

    constexpr size_t NACT = (size_t)M_ * K_;      // 4 Mi elements
    constexpr size_t NW   = (size_t)H_ * H_;      // 1 Mi elements
    _Float16* p = (_Float16*)d_ws;
    _Float16* q16  = p;                       // 8 MB
    _Float16* k16  = p + NACT;                // 8 MB
    _Float16* v16  = p + 2 * NACT;            // 8 MB
    _Float16* w16q = p + 3 * NACT;            // 2 MB
    _Float16* w16k = w16q + NW;
    _Float16* w16v = w16k + NW;
    _Float16* w16o = w16v + NW;
    _Float16* qh   = w16o + NW;               // 8 MB
    _Float16* kh   = qh + NACT;               // 8 MB
    _Float16* vt   = kh + NACT;               // 8 MB
    _Float16* ctx  = q16;                     // alias: q16 dead after proj GEMMs

    CvtArgs ca;
    ca.s[0] = q;  ca.d[0] = q16;  ca.n[0] = (int)NACT;
    ca.s[1] = v;  ca.d[1] = v16;  ca.n[1] = (int)NACT;
    ca.s[2] = k;  ca.d[2] = k16;  ca.n[2] = (int)NACT;
    ca.s[3] = Wq; ca.d[3] = w16q; ca.n[3] = (int)NW;
    ca.s[4] = Wk; ca.d[4] = w16k; ca.n[4] = (int)NW;
    ca.s[5] = Wv; ca.d[5] = w16v; ca.n[5] = (int)NW;
    ca.s[6] = Wo; ca.d[6] = w16o; ca.n[6] = (int)NW;
    cvt7<<<dim3(2048, 7), 256, 0, stream>>>(ca);

    const dim3 gg(H_ / 64, M_ / 128);   // 16 x 32
    gemm16<0><<<gg, 256, 0, stream>>>(q16, w16q, bq, qh, 0.125f);
    gemm16<0><<<gg, 256, 0, stream>>>(k16, w16k, bk, kh, 1.0f);
    gemm16<1><<<gg, 256, 0, stream>>>(v16, w16v, bv, vt, 1.0f);

    attn_mfma<<<dim3(S_ / 64, B_ * NH_), 256, 0, stream>>>(qh, kh, vt, ctx);

    gemm16<2><<<gg, 256, 0, stream>>>(ctx, w16o, bo, out, 1.0f);
}